// Round 9
// baseline (286.135 us; speedup 1.0000x reference)
//
#include <hip/hip_runtime.h>
#include <hip/hip_bf16.h>
#include <stdint.h>

// B=16, K=8, N=196, D=768, H=3072, DOUT=768
// y[b,n,:] = (mean_k relu(slots[b,k]@W1 + pos[n]@W1 + b1)) @ W2 + b2
// (softmax over K of K-identical values is exactly 1/K; map_alpha unused)
//
// SINGLE normal-launch kernel, 384 blocks x 512 threads, manual grid barriers
// (device-scope atomics + __threadfence; one-shot slots init'd from poisoned ws
// via block0 + MAGIC ready flag). Co-residency guaranteed: launch_bounds(512,4)
// -> VGPR<=128, LDS 48KB -> >=2 blocks/CU -> capacity 512 >= 384.
//  A: prep (W1t/A1/W2t atoms)  B: GEMM1 144 tiles (BM64xBN128)
//  C: hbar -> Hb atoms (2400)  D: GEMM2 300 tiles (BM128xBN64, rt-XCD swizzle)
// Atom = 64x64 bf16 tile, image [kb 0..7][r 0..63] chunks of 8; off=(kb*64+r)*8.

typedef __attribute__((ext_vector_type(8))) short bf16x8;
typedef __attribute__((ext_vector_type(4))) float f32x4;

#define AS1 __attribute__((address_space(1)))
#define AS3 __attribute__((address_space(3)))

#define WAIT_VM(N) asm volatile("s_waitcnt vmcnt(" #N ")" ::: "memory")
#define BAR()      asm volatile("s_barrier" ::: "memory")
#define BAR_LDS()  asm volatile("s_waitcnt lgkmcnt(0)\ns_barrier" ::: "memory")

#define NB 384u
#define MAGIC 0x13572468u

static __device__ __forceinline__ void gld_lds16(const void* g, void* l) {
    __builtin_amdgcn_global_load_lds((const AS1 unsigned int*)g,
                                     (AS3 unsigned int*)l, 16, 0, 0);
}

static __device__ __forceinline__ unsigned short f2bf(float f) {
    union { float f; unsigned int u; } v; v.f = f;
    unsigned int u = v.u;
    return (unsigned short)((u + 0x7fffu + ((u >> 16) & 1u)) >> 16);  // RNE
}

static __device__ __forceinline__ void grid_barrier(unsigned* slot) {
    __syncthreads();
    if (threadIdx.x == 0) {
        __threadfence();   // agent fence: flush this XCD's L2 (release side)
        __hip_atomic_fetch_add(slot, 1u, __ATOMIC_ACQ_REL, __HIP_MEMORY_SCOPE_AGENT);
        while (__hip_atomic_load(slot, __ATOMIC_RELAXED, __HIP_MEMORY_SCOPE_AGENT) < NB)
            __builtin_amdgcn_s_sleep(16);
        __threadfence();   // acquire side: invalidate stale L1/L2
    }
    __syncthreads();
}

__launch_bounds__(512, 4)
__global__ void k_fused(const float* __restrict__ slots, const float* __restrict__ pos,
                        const float* __restrict__ W1, const float* __restrict__ b1,
                        const float* __restrict__ W2, const float* __restrict__ b2,
                        unsigned* __restrict__ bar,
                        unsigned short* __restrict__ W1t, unsigned short* __restrict__ W2t,
                        unsigned short* __restrict__ A1, float* __restrict__ C1,
                        unsigned short* __restrict__ Hb, float* __restrict__ out) {
    __shared__ unsigned short sm[2 * 12288];   // 48 KB: 2 stages x 24 KB
    const int tid  = threadIdx.x;
    const int lane = tid & 63;
    const int wave = tid >> 6;                 // 0..7
    const int q    = lane >> 4;
    const int l16  = lane & 15;

    // init one-shot barrier slots (ws is poisoned 0xAA before every launch)
    if (blockIdx.x == 0 && tid == 0) {
        __hip_atomic_store(&bar[1], 0u, __ATOMIC_RELAXED, __HIP_MEMORY_SCOPE_AGENT);
        __hip_atomic_store(&bar[2], 0u, __ATOMIC_RELAXED, __HIP_MEMORY_SCOPE_AGENT);
        __hip_atomic_store(&bar[3], 0u, __ATOMIC_RELAXED, __HIP_MEMORY_SCOPE_AGENT);
        __hip_atomic_store(&bar[0], MAGIC, __ATOMIC_RELEASE, __HIP_MEMORY_SCOPE_AGENT);
    }

    // ================= Phase A: prep =================
    for (int idx = blockIdx.x * 512 + tid; idx < 626688; idx += NB * 512) {
        if (idx < 294912) {                    // W1t (r fastest -> coalesced)
            int r  = idx % 3072;
            int kc = idx / 3072;               // 0..95
            unsigned int po[4];
            #pragma unroll
            for (int j = 0; j < 4; ++j) {
                unsigned short lo = f2bf(W1[(size_t)(kc * 8 + 2 * j) * 3072 + r]);
                unsigned short hi = f2bf(W1[(size_t)(kc * 8 + 2 * j + 1) * 3072 + r]);
                po[j] = (unsigned int)lo | ((unsigned int)hi << 16);
            }
            size_t dst = ((size_t)(r >> 6) * 12 + (kc >> 3)) * 4096
                       + (size_t)((kc & 7) * 64 + (r & 63)) * 8;
            *(uint4*)(W1t + dst) = make_uint4(po[0], po[1], po[2], po[3]);
        } else if (idx < 331776) {             // A1 pack
            int t = idx - 294912;
            int r  = t % 384;
            int kc = t / 384;                  // 0..95
            uint4 o = make_uint4(0u, 0u, 0u, 0u);
            if (r < 324) {
                const float* src = (r < 128) ? (slots + (size_t)r * 768 + kc * 8)
                                             : (pos + (size_t)(r - 128) * 768 + kc * 8);
                float4 a = *(const float4*)(src);
                float4 b = *(const float4*)(src + 4);
                o.x = (unsigned int)f2bf(a.x) | ((unsigned int)f2bf(a.y) << 16);
                o.y = (unsigned int)f2bf(a.z) | ((unsigned int)f2bf(a.w) << 16);
                o.z = (unsigned int)f2bf(b.x) | ((unsigned int)f2bf(b.y) << 16);
                o.w = (unsigned int)f2bf(b.z) | ((unsigned int)f2bf(b.w) << 16);
            }
            size_t dst = ((size_t)(r >> 6) * 12 + (kc >> 3)) * 4096
                       + (size_t)((kc & 7) * 64 + (r & 63)) * 8;
            *(uint4*)(A1 + dst) = o;
        } else {                               // W2t
            int t = idx - 331776;
            int r  = t % 768;
            int kc = t / 768;                  // 0..383
            unsigned int po[4];
            #pragma unroll
            for (int j = 0; j < 4; ++j) {
                unsigned short lo = f2bf(W2[(size_t)(kc * 8 + 2 * j) * 768 + r]);
                unsigned short hi = f2bf(W2[(size_t)(kc * 8 + 2 * j + 1) * 768 + r]);
                po[j] = (unsigned int)lo | ((unsigned int)hi << 16);
            }
            size_t dst = ((size_t)(r >> 6) * 48 + (kc >> 3)) * 4096
                       + (size_t)((kc & 7) * 64 + (r & 63)) * 8;
            *(uint4*)(W2t + dst) = make_uint4(po[0], po[1], po[2], po[3]);
        }
    }
    // barrier 0 (waits for slot init via MAGIC first)
    __syncthreads();
    if (tid == 0) {
        while (__hip_atomic_load(&bar[0], __ATOMIC_RELAXED, __HIP_MEMORY_SCOPE_AGENT) != MAGIC)
            __builtin_amdgcn_s_sleep(16);
        __threadfence();
        __hip_atomic_fetch_add(&bar[1], 1u, __ATOMIC_ACQ_REL, __HIP_MEMORY_SCOPE_AGENT);
        while (__hip_atomic_load(&bar[1], __ATOMIC_RELAXED, __HIP_MEMORY_SCOPE_AGENT) < NB)
            __builtin_amdgcn_s_sleep(16);
        __threadfence();
    }
    __syncthreads();

    // ================= Phase B: GEMM1, 144 tiles (BM=64, BN=128) =================
    if (blockIdx.x < 144) {
        const int rt = blockIdx.x / 24;        // 0..5
        const int nt = blockIdx.x % 24;        // 0..23
        const unsigned short* Ab = A1  + (size_t)rt * 12 * 4096;
        const unsigned short* B0 = W1t + (size_t)(2 * nt)     * 12 * 4096;
        const unsigned short* B1 = W1t + (size_t)(2 * nt + 1) * 12 * 4096;
        const int wm = wave >> 2;              // 0..1 (32-row half)
        const int wn = wave & 3;               // 0..3 (32-col quarter of 128)
        f32x4 acc[2][2] = {};
        auto stage = [&](int i, unsigned short* d) {   // 3 loads/thread
            gld_lds16(Ab + (size_t)i * 4096 + tid * 8, d + tid * 8);
            gld_lds16(B0 + (size_t)i * 4096 + tid * 8, d + 4096 + tid * 8);
            gld_lds16(B1 + (size_t)i * 4096 + tid * 8, d + 8192 + tid * 8);
        };
        const int aoff = (wm * 32 + l16) * 8;
        const int boff = 4096 + (wn >> 1) * 4096 + ((wn & 1) * 32 + l16) * 8;
        auto compute = [&](const unsigned short* buf) {
            #pragma unroll
            for (int ks = 0; ks < 2; ++ks) {
                const int ko = (ks * 4 + q) * 512;
                bf16x8 af0 = *(const bf16x8*)(buf + ko + aoff);
                bf16x8 af1 = *(const bf16x8*)(buf + ko + aoff + 128);
                bf16x8 bf0 = *(const bf16x8*)(buf + ko + boff);
                bf16x8 bf1 = *(const bf16x8*)(buf + ko + boff + 128);
                acc[0][0] = __builtin_amdgcn_mfma_f32_16x16x32_bf16(af0, bf0, acc[0][0], 0, 0, 0);
                acc[0][1] = __builtin_amdgcn_mfma_f32_16x16x32_bf16(af0, bf1, acc[0][1], 0, 0, 0);
                acc[1][0] = __builtin_amdgcn_mfma_f32_16x16x32_bf16(af1, bf0, acc[1][0], 0, 0, 0);
                acc[1][1] = __builtin_amdgcn_mfma_f32_16x16x32_bf16(af1, bf1, acc[1][1], 0, 0, 0);
            }
        };
        stage(0, sm);
        #pragma unroll 1
        for (int i = 0; i < 12; ++i) {
            unsigned short* cur = sm + (i & 1) * 12288;
            unsigned short* nxt = sm + ((i + 1) & 1) * 12288;
            if (i + 1 < 12) { stage(i + 1, nxt); WAIT_VM(3); } else { WAIT_VM(0); }
            BAR();
            compute(cur);
            if (i + 1 < 12) BAR_LDS();
        }
        const int row0 = rt * 64 + wm * 32;
        const int col0 = nt * 128 + ((wn >> 1) * 64) + (wn & 1) * 32;
        #pragma unroll
        for (int ii = 0; ii < 2; ++ii) {
            #pragma unroll
            for (int jj = 0; jj < 2; ++jj) {
                int col = col0 + jj * 16 + l16;
                #pragma unroll
                for (int r = 0; r < 4; ++r) {
                    int row = row0 + ii * 16 + q * 4 + r;
                    if (row < 324) C1[(size_t)row * 3072 + col] = acc[ii][jj][r];
                }
            }
        }
    }
    grid_barrier(&bar[2]);

    // ================= Phase C: hbar (2400 units of 8 waves) =================
    for (int u = blockIdx.x; u < 2400; u += NB) {
        const int bx = u / 48;                 // row-atom 0..49
        const int hg = u - bx * 48;            // 0..47
        const int hc = hg * 8 + wave;          // 0..383
        const int h0 = hc * 8;
        int bn = bx * 64 + lane;
        if (bn > 3135) bn = 3135;              // clamp (dup rows never stored)
        const int b = bn / 196;
        const int n = bn - b * 196;
        const float* prow = C1 + (size_t)(128 + n) * 3072 + h0;
        float4 pA = *(const float4*)(prow);
        float4 pB = *(const float4*)(prow + 4);
        float4 bA = *(const float4*)(b1 + h0);
        float4 bB = *(const float4*)(b1 + h0 + 4);
        float pb[8] = { pA.x + bA.x, pA.y + bA.y, pA.z + bA.z, pA.w + bA.w,
                        pB.x + bB.x, pB.y + bB.y, pB.z + bB.z, pB.w + bB.w };
        float acc[8] = {};
        #pragma unroll
        for (int k = 0; k < 8; ++k) {
            const float* srow = C1 + (size_t)(b * 8 + k) * 3072 + h0;
            float4 sA_ = *(const float4*)(srow);
            float4 sB_ = *(const float4*)(srow + 4);
            acc[0] += fmaxf(sA_.x + pb[0], 0.f);
            acc[1] += fmaxf(sA_.y + pb[1], 0.f);
            acc[2] += fmaxf(sA_.z + pb[2], 0.f);
            acc[3] += fmaxf(sA_.w + pb[3], 0.f);
            acc[4] += fmaxf(sB_.x + pb[4], 0.f);
            acc[5] += fmaxf(sB_.y + pb[5], 0.f);
            acc[6] += fmaxf(sB_.z + pb[6], 0.f);
            acc[7] += fmaxf(sB_.w + pb[7], 0.f);
        }
        unsigned int w0 = (unsigned int)f2bf(acc[0] * 0.125f) | ((unsigned int)f2bf(acc[1] * 0.125f) << 16);
        unsigned int w1 = (unsigned int)f2bf(acc[2] * 0.125f) | ((unsigned int)f2bf(acc[3] * 0.125f) << 16);
        unsigned int w2 = (unsigned int)f2bf(acc[4] * 0.125f) | ((unsigned int)f2bf(acc[5] * 0.125f) << 16);
        unsigned int w3 = (unsigned int)f2bf(acc[6] * 0.125f) | ((unsigned int)f2bf(acc[7] * 0.125f) << 16);
        size_t dst = ((size_t)bx * 48 + hg) * 4096 + (size_t)(wave * 64 + lane) * 8;
        *(uint4*)(Hb + dst) = make_uint4(w0, w1, w2, w3);
    }
    grid_barrier(&bar[3]);

    // ================= Phase D: GEMM2, 300 tiles (BM=128, BN=64) =================
    if (blockIdx.x < 300) {
        const int id = blockIdx.x;
        int rt, nt;
        if (id < 288) { rt = (id / 96) * 8 + (id & 7); nt = (id % 96) >> 3; }
        else          { rt = 24; nt = id - 288; }
        const unsigned short* A0b = Hb  + ((size_t)(2 * rt)     * 48) * 4096;
        const unsigned short* A1b = Hb  + ((size_t)(2 * rt + 1) * 48) * 4096;
        const unsigned short* Bb  = W2t + ((size_t)nt * 48) * 4096;
        const int wm = wave >> 1, wn = wave & 1;   // wm 0..3 (M), wn 0..1 (N)
        f32x4 acc[2][2] = {};
        auto stage = [&](int i, unsigned short* d) {   // 3 loads/thread
            gld_lds16(A0b + (size_t)i * 4096 + tid * 8, d + tid * 8);
            gld_lds16(A1b + (size_t)i * 4096 + tid * 8, d + 4096 + tid * 8);
            gld_lds16(Bb  + (size_t)i * 4096 + tid * 8, d + 8192 + tid * 8);
        };
        const int r0 = wm * 32 + l16;
        const int aoff0 = (r0 >> 6) * 4096 + (r0 & 63) * 8;
        const int r1 = wm * 32 + 16 + l16;
        const int aoff1 = (r1 >> 6) * 4096 + (r1 & 63) * 8;
        const int boff  = 8192 + (wn * 32 + l16) * 8;
        auto compute = [&](const unsigned short* buf) {
            #pragma unroll
            for (int ks = 0; ks < 2; ++ks) {
                const int ko = (ks * 4 + q) * 512;
                bf16x8 af0 = *(const bf16x8*)(buf + aoff0 + ko);
                bf16x8 af1 = *(const bf16x8*)(buf + aoff1 + ko);
                bf16x8 bf0 = *(const bf16x8*)(buf + boff + ko);
                bf16x8 bf1 = *(const bf16x8*)(buf + boff + ko + 128);
                acc[0][0] = __builtin_amdgcn_mfma_f32_16x16x32_bf16(af0, bf0, acc[0][0], 0, 0, 0);
                acc[0][1] = __builtin_amdgcn_mfma_f32_16x16x32_bf16(af0, bf1, acc[0][1], 0, 0, 0);
                acc[1][0] = __builtin_amdgcn_mfma_f32_16x16x32_bf16(af1, bf0, acc[1][0], 0, 0, 0);
                acc[1][1] = __builtin_amdgcn_mfma_f32_16x16x32_bf16(af1, bf1, acc[1][1], 0, 0, 0);
            }
        };
        stage(0, sm);
        #pragma unroll 1
        for (int i = 0; i < 48; ++i) {
            unsigned short* cur = sm + (i & 1) * 12288;
            unsigned short* nxt = sm + ((i + 1) & 1) * 12288;
            if (i + 1 < 48) { stage(i + 1, nxt); WAIT_VM(3); } else { WAIT_VM(0); }
            BAR();
            compute(cur);
            if (i + 1 < 48) BAR_LDS();
        }
        const int row0 = rt * 128 + wm * 32;
        const int col0 = nt * 64 + wn * 32;
        #pragma unroll
        for (int ii = 0; ii < 2; ++ii) {
            #pragma unroll
            for (int jj = 0; jj < 2; ++jj) {
                int col = col0 + jj * 16 + l16;
                float bv = b2[col];
                #pragma unroll
                for (int r = 0; r < 4; ++r) {
                    int row = row0 + ii * 16 + q * 4 + r;
                    if (row < 3136) out[(size_t)row * 768 + col] = acc[ii][jj][r] + bv;
                }
            }
        }
    }
}

extern "C" void kernel_launch(void* const* d_in, const int* in_sizes, int n_in,
                              void* d_out, int out_size, void* d_ws, size_t ws_size,
                              hipStream_t stream) {
    const float* slots  = (const float*)d_in[0];   // 16*8*768
    const float* pos    = (const float*)d_in[1];   // 196*768
    // d_in[2] = map_alpha: unused (softmax over K of identical values = 1/K)
    const float* W1     = (const float*)d_in[3];   // 768*3072
    const float* b1     = (const float*)d_in[4];   // 3072
    const float* W2     = (const float*)d_in[5];   // 3072*768
    const float* b2     = (const float*)d_in[6];   // 768
    float* out = (float*)d_out;                    // 3136*768 f32

    size_t off = 0;
    auto alloc = [&](size_t bytes) {
        void* p = (char*)d_ws + off;
        off += (bytes + 255) & ~(size_t)255;
        return p;
    };
    unsigned*       bar = (unsigned*)alloc(256);                              // barrier slots
    unsigned short* W1t = (unsigned short*)alloc((size_t)3072 * 768 * 2);     // [48][12] atoms
    unsigned short* W2t = (unsigned short*)alloc((size_t)768 * 3072 * 2);     // [12][48] atoms
    unsigned short* A1  = (unsigned short*)alloc((size_t)384 * 768 * 2);      // [6][12] atoms
    float*          C1  = (float*)alloc((size_t)384 * 3072 * 4);              // row-major
    unsigned short* Hb  = (unsigned short*)alloc((size_t)50 * 48 * 4096 * 2); // [50][48] atoms

    k_fused<<<384, 512, 0, stream>>>(slots, pos, W1, b1, W2, b2,
                                     bar, W1t, W2t, A1, C1, Hb, out);
}

// Round 10
// 128.461 us; speedup vs baseline: 2.2274x; 2.2274x over previous
//
#include <hip/hip_runtime.h>
#include <hip/hip_bf16.h>
#include <stdint.h>

// B=16, K=8, N=196, D=768, H=3072, DOUT=768
// y[b,n,:] = (mean_k relu(slots[b,k]@W1 + pos[n]@W1 + b1)) @ W2 + b2
// (softmax over K of K-identical values is exactly 1/K; map_alpha unused)
//
// Dispatches (R7 structure, W2t moved to dispatch 2):
//  k_prep:      W1->W1t atoms + A1=[slots;pos] atoms (bf16)
//  k_gemm1_w2t: C1 = A1 @ W1t^T (288 tiles, XCD nt-swizzle) + W2->W2t (1152 blks)
//  k_hbar:      Hb atoms (50 row-atoms, clamped)
//  k_gemm2:     out = Hb @ W2t^T + b2 (BM=128,BN=64, 512 thr, 3-stage,
//               XCD rt-partition swizzle)
// Atom = 64x64 bf16 tile, image [kb 0..7][r 0..63] chunks of 8; off=(kb*64+r)*8.

typedef __attribute__((ext_vector_type(8))) short bf16x8;
typedef __attribute__((ext_vector_type(4))) float f32x4;

#define AS1 __attribute__((address_space(1)))
#define AS3 __attribute__((address_space(3)))

#define WAIT_VM(N) asm volatile("s_waitcnt vmcnt(" #N ")" ::: "memory")
#define BAR()      asm volatile("s_barrier" ::: "memory")
#define BAR_LDS()  asm volatile("s_waitcnt lgkmcnt(0)\ns_barrier" ::: "memory")

static __device__ __forceinline__ void gld_lds16(const void* g, void* l) {
    __builtin_amdgcn_global_load_lds((const AS1 unsigned int*)g,
                                     (AS3 unsigned int*)l, 16, 0, 0);
}

static __device__ __forceinline__ unsigned short f2bf(float f) {
    union { float f; unsigned int u; } v; v.f = f;
    unsigned int u = v.u;
    return (unsigned short)((u + 0x7fffu + ((u >> 16) & 1u)) >> 16);  // RNE
}

// ---------------- prep: W1t tiled transpose + A1 tiled pack ----------------
__global__ void k_prep(const float* __restrict__ W1, unsigned short* __restrict__ W1t,
                       const float* __restrict__ S, const float* __restrict__ P,
                       unsigned short* __restrict__ A1) {
    int idx = blockIdx.x * blockDim.x + threadIdx.x;
    const int C1n = 96 * 3072;          // W1t tasks
    const int PKn = 96 * 384;           // A1 tasks
    if (idx < C1n) {
        int r  = idx % 3072;            // consecutive tid -> consecutive r (coalesced)
        int kc = idx / 3072;            // 8-elem k-chunk (0..95)
        unsigned int po[4];
        #pragma unroll
        for (int j = 0; j < 4; ++j) {
            unsigned short lo = f2bf(W1[(size_t)(kc * 8 + 2 * j) * 3072 + r]);
            unsigned short hi = f2bf(W1[(size_t)(kc * 8 + 2 * j + 1) * 3072 + r]);
            po[j] = (unsigned int)lo | ((unsigned int)hi << 16);
        }
        size_t dst = ((size_t)(r >> 6) * 12 + (kc >> 3)) * 4096
                   + (size_t)((kc & 7) * 64 + (r & 63)) * 8;
        *(uint4*)(W1t + dst) = make_uint4(po[0], po[1], po[2], po[3]);
    } else if (idx < C1n + PKn) {
        int t = idx - C1n;
        int r  = t % 384;
        int kc = t / 384;
        uint4 o = make_uint4(0u, 0u, 0u, 0u);
        if (r < 324) {
            const float* src = (r < 128) ? (S + (size_t)r * 768 + kc * 8)
                                         : (P + (size_t)(r - 128) * 768 + kc * 8);
            float4 a = *(const float4*)(src);
            float4 b = *(const float4*)(src + 4);
            o.x = (unsigned int)f2bf(a.x) | ((unsigned int)f2bf(a.y) << 16);
            o.y = (unsigned int)f2bf(a.z) | ((unsigned int)f2bf(a.w) << 16);
            o.z = (unsigned int)f2bf(b.x) | ((unsigned int)f2bf(b.y) << 16);
            o.w = (unsigned int)f2bf(b.z) | ((unsigned int)f2bf(b.w) << 16);
        }
        size_t dst = ((size_t)(r >> 6) * 12 + (kc >> 3)) * 4096
                   + (size_t)((kc & 7) * 64 + (r & 63)) * 8;
        *(uint4*)(A1 + dst) = o;
    }
}

// ---- GEMM1 (288 tiles, BM=BN=64, 3-stage, XCD nt-swizzle) + W2t (1152 blocks) ----
__launch_bounds__(256)
__global__ void k_gemm1_w2t(const unsigned short* __restrict__ A,
                            const unsigned short* __restrict__ Bt,
                            float* __restrict__ C,
                            const float* __restrict__ W2,
                            unsigned short* __restrict__ W2t) {
    const int tid = threadIdx.x;
    if (blockIdx.x >= 288) {            // ---- W2t conversion ----
        int idx = (blockIdx.x - 288) * 256 + tid;    // 0..294911
        int r  = idx % 768;
        int kc = idx / 768;             // 0..383
        unsigned int po[4];
        #pragma unroll
        for (int j = 0; j < 4; ++j) {
            unsigned short lo = f2bf(W2[(size_t)(kc * 8 + 2 * j) * 768 + r]);
            unsigned short hi = f2bf(W2[(size_t)(kc * 8 + 2 * j + 1) * 768 + r]);
            po[j] = (unsigned int)lo | ((unsigned int)hi << 16);
        }
        size_t dst = ((size_t)(r >> 6) * 48 + (kc >> 3)) * 4096
                   + (size_t)((kc & 7) * 64 + (r & 63)) * 8;
        *(uint4*)(W2t + dst) = make_uint4(po[0], po[1], po[2], po[3]);
        return;
    }

    __shared__ unsigned short sm[3 * 8192];   // 48 KB
    const int lane = tid & 63;
    const int wave = tid >> 6;
    const int wm = wave >> 1, wn = wave & 1;
    const int q = lane >> 4, l16 = lane & 15;

    // swizzle: XCD x = id&7 owns nt in [6x, 6x+6) -> W1t slice L2-resident
    const int id = blockIdx.x;
    const int j  = id >> 3;
    const int nt = (id & 7) * 6 + j % 6;
    const int rt = j / 6;

    const unsigned short* Ab = A  + (size_t)rt * 12 * 4096;
    const unsigned short* Bb = Bt + (size_t)nt * 12 * 4096;

    f32x4 acc[2][2] = {};
    const int offA = (wm * 32 + l16) * 8;
    const int offB = 4096 + (wn * 32 + l16) * 8;

    auto stage = [&](int i, unsigned short* d) {     // 4 loads/thread
        const unsigned short* Ag = Ab + (size_t)i * 4096;
        const unsigned short* Bg = Bb + (size_t)i * 4096;
        gld_lds16(Ag + tid * 8,        d + tid * 8);
        gld_lds16(Ag + 2048 + tid * 8, d + 2048 + tid * 8);
        gld_lds16(Bg + tid * 8,        d + 4096 + tid * 8);
        gld_lds16(Bg + 2048 + tid * 8, d + 6144 + tid * 8);
    };
    auto compute = [&](const unsigned short* buf) {
        #pragma unroll
        for (int ks = 0; ks < 2; ++ks) {
            const int ko = (ks * 4 + q) * 512;
            bf16x8 af0 = *(const bf16x8*)(buf + ko + offA);
            bf16x8 af1 = *(const bf16x8*)(buf + ko + offA + 128);
            bf16x8 bf0 = *(const bf16x8*)(buf + ko + offB);
            bf16x8 bf1 = *(const bf16x8*)(buf + ko + offB + 128);
            acc[0][0] = __builtin_amdgcn_mfma_f32_16x16x32_bf16(af0, bf0, acc[0][0], 0, 0, 0);
            acc[0][1] = __builtin_amdgcn_mfma_f32_16x16x32_bf16(af0, bf1, acc[0][1], 0, 0, 0);
            acc[1][0] = __builtin_amdgcn_mfma_f32_16x16x32_bf16(af1, bf0, acc[1][0], 0, 0, 0);
            acc[1][1] = __builtin_amdgcn_mfma_f32_16x16x32_bf16(af1, bf1, acc[1][1], 0, 0, 0);
        }
    };

    unsigned short* s0 = sm;
    unsigned short* s1 = sm + 8192;
    unsigned short* s2 = sm + 16384;

    stage(0, s0);
    stage(1, s1);
    for (int i = 0; i < 12; i += 3) {
        stage(i + 2, s2); WAIT_VM(8);
        BAR(); compute(s0); BAR_LDS();
        if (i + 3 < 12) { stage(i + 3, s0); WAIT_VM(8); } else { WAIT_VM(4); }
        BAR(); compute(s1); BAR_LDS();
        if (i + 4 < 12) { stage(i + 4, s1); WAIT_VM(8); }
        else if (i + 3 < 12) { WAIT_VM(4); }
        else { WAIT_VM(0); }
        BAR(); compute(s2);
        if (i + 3 < 12) BAR_LDS();
    }

    const int row0 = rt * 64 + wm * 32;
    const int col0 = nt * 64 + wn * 32;
    #pragma unroll
    for (int ii = 0; ii < 2; ++ii) {
        #pragma unroll
        for (int jj = 0; jj < 2; ++jj) {
            int col = col0 + jj * 16 + l16;
            #pragma unroll
            for (int r = 0; r < 4; ++r) {
                int row = row0 + ii * 16 + q * 4 + r;
                if (row < 324) C[(size_t)row * 3072 + col] = acc[ii][jj][r];
            }
        }
    }
}

// ---- hbar: Hb atoms (50 row-atoms w/ clamp), 4800 blocks ----
__global__ void k_hbar(const float* __restrict__ C1, const float* __restrict__ b1,
                       unsigned short* __restrict__ Hb) {
    const int bid  = blockIdx.x;
    const int tid  = threadIdx.x;
    const int bx   = bid % 50;                     // row-atom 0..49
    const int yq   = bid / 50;                     // 0..95
    const int lane = tid & 63;
    const int wv   = tid >> 6;
    const int hc   = yq * 4 + wv;                  // 0..383
    const int h0   = hc * 8;
    int bn = bx * 64 + lane;
    if (bn > 3135) bn = 3135;                      // clamp (dup rows never stored)
    const int b = bn / 196;
    const int n = bn - b * 196;
    const float* prow = C1 + (size_t)(128 + n) * 3072 + h0;
    float4 pA = *(const float4*)(prow);
    float4 pB = *(const float4*)(prow + 4);
    float4 bA = *(const float4*)(b1 + h0);
    float4 bB = *(const float4*)(b1 + h0 + 4);
    float pb[8] = { pA.x + bA.x, pA.y + bA.y, pA.z + bA.z, pA.w + bA.w,
                    pB.x + bB.x, pB.y + bB.y, pB.z + bB.z, pB.w + bB.w };
    float acc[8] = {};
    #pragma unroll
    for (int k = 0; k < 8; ++k) {
        const float* srow = C1 + (size_t)(b * 8 + k) * 3072 + h0;  // wave-broadcast-ish
        float4 sA_ = *(const float4*)(srow);
        float4 sB_ = *(const float4*)(srow + 4);
        acc[0] += fmaxf(sA_.x + pb[0], 0.f);
        acc[1] += fmaxf(sA_.y + pb[1], 0.f);
        acc[2] += fmaxf(sA_.z + pb[2], 0.f);
        acc[3] += fmaxf(sA_.w + pb[3], 0.f);
        acc[4] += fmaxf(sB_.x + pb[4], 0.f);
        acc[5] += fmaxf(sB_.y + pb[5], 0.f);
        acc[6] += fmaxf(sB_.z + pb[6], 0.f);
        acc[7] += fmaxf(sB_.w + pb[7], 0.f);
    }
    unsigned int w0 = (unsigned int)f2bf(acc[0] * 0.125f) | ((unsigned int)f2bf(acc[1] * 0.125f) << 16);
    unsigned int w1 = (unsigned int)f2bf(acc[2] * 0.125f) | ((unsigned int)f2bf(acc[3] * 0.125f) << 16);
    unsigned int w2 = (unsigned int)f2bf(acc[4] * 0.125f) | ((unsigned int)f2bf(acc[5] * 0.125f) << 16);
    unsigned int w3 = (unsigned int)f2bf(acc[6] * 0.125f) | ((unsigned int)f2bf(acc[7] * 0.125f) << 16);
    size_t dst = ((size_t)bx * 48 + (hc >> 3)) * 4096
               + (size_t)((hc & 7) * 64 + lane) * 8;
    *(uint4*)(Hb + dst) = make_uint4(w0, w1, w2, w3);
}

// ---- GEMM2: BM=128, BN=64, 512 threads (8 waves 4x2), 3-stage, rt-XCD swizzle ----
// Hb atoms [50][48][4096]; W2t atoms [12][48][4096]; out 3136x768 f32 + b2.
__launch_bounds__(512)
__global__ void k_gemm2(const unsigned short* __restrict__ Hb,
                        const unsigned short* __restrict__ W2t,
                        const float* __restrict__ b2, float* __restrict__ out) {
    __shared__ unsigned short sm[3 * 12288];   // 72 KB -> 2 blocks/CU (16 waves)

    const int tid  = threadIdx.x;
    const int lane = tid & 63;
    const int wave = tid >> 6;                 // 0..7
    const int wm = wave >> 1, wn = wave & 1;   // wm 0..3 (M), wn 0..1 (N)
    const int q = lane >> 4, l16 = lane & 15;

    // rt-partition swizzle: XCD x = id&7 handles rt in {x, x+8, x+16} (+ tail rt 24)
    const int id = blockIdx.x;
    int rt, nt;
    if (id < 288) { rt = (id / 96) * 8 + (id & 7); nt = (id % 96) >> 3; }
    else          { rt = 24; nt = id - 288; }

    const unsigned short* A0b = Hb  + ((size_t)(2 * rt)     * 48) * 4096;
    const unsigned short* A1b = Hb  + ((size_t)(2 * rt + 1) * 48) * 4096;
    const unsigned short* Bb  = W2t + ((size_t)nt * 48) * 4096;

    f32x4 acc[2][2] = {};

    auto stage = [&](int i, unsigned short* d) {     // 3 loads/thread (512 thr)
        gld_lds16(A0b + (size_t)i * 4096 + tid * 8, d + tid * 8);
        gld_lds16(A1b + (size_t)i * 4096 + tid * 8, d + 4096 + tid * 8);
        gld_lds16(Bb  + (size_t)i * 4096 + tid * 8, d + 8192 + tid * 8);
    };

    const int r0 = wm * 32 + l16;
    const int aoff0 = (r0 >> 6) * 4096 + (r0 & 63) * 8;
    const int r1 = wm * 32 + 16 + l16;
    const int aoff1 = (r1 >> 6) * 4096 + (r1 & 63) * 8;
    const int boff  = 8192 + (wn * 32 + l16) * 8;

    auto compute = [&](const unsigned short* buf) {
        #pragma unroll
        for (int ks = 0; ks < 2; ++ks) {
            const int ko = (ks * 4 + q) * 512;       // k-chunk offset within atom
            bf16x8 af0 = *(const bf16x8*)(buf + aoff0 + ko);
            bf16x8 af1 = *(const bf16x8*)(buf + aoff1 + ko);
            bf16x8 bf0 = *(const bf16x8*)(buf + boff + ko);
            bf16x8 bf1 = *(const bf16x8*)(buf + boff + ko + 128);
            acc[0][0] = __builtin_amdgcn_mfma_f32_16x16x32_bf16(af0, bf0, acc[0][0], 0, 0, 0);
            acc[0][1] = __builtin_amdgcn_mfma_f32_16x16x32_bf16(af0, bf1, acc[0][1], 0, 0, 0);
            acc[1][0] = __builtin_amdgcn_mfma_f32_16x16x32_bf16(af1, bf0, acc[1][0], 0, 0, 0);
            acc[1][1] = __builtin_amdgcn_mfma_f32_16x16x32_bf16(af1, bf1, acc[1][1], 0, 0, 0);
        }
    };

    unsigned short* s0 = sm;
    unsigned short* s1 = sm + 12288;
    unsigned short* s2 = sm + 24576;

    stage(0, s0);
    stage(1, s1);
    for (int i = 0; i < 48; i += 3) {
        stage(i + 2, s2); WAIT_VM(6);
        BAR(); compute(s0); BAR_LDS();
        if (i + 3 < 48) { stage(i + 3, s0); WAIT_VM(6); } else { WAIT_VM(3); }
        BAR(); compute(s1); BAR_LDS();
        if (i + 4 < 48) { stage(i + 4, s1); WAIT_VM(6); }
        else if (i + 3 < 48) { WAIT_VM(3); }
        else { WAIT_VM(0); }
        BAR(); compute(s2);
        if (i + 3 < 48) BAR_LDS();
    }

    // epilogue: C/D col=lane&15, row=(lane>>4)*4+reg
    const int row0 = rt * 128 + wm * 32;
    const int col0 = nt * 64 + wn * 32;
    #pragma unroll
    for (int ii = 0; ii < 2; ++ii) {
        #pragma unroll
        for (int jj = 0; jj < 2; ++jj) {
            int col = col0 + jj * 16 + l16;
            float bv = b2[col];
            #pragma unroll
            for (int r = 0; r < 4; ++r) {
                int row = row0 + ii * 16 + q * 4 + r;
                if (row < 3136) out[(size_t)row * 768 + col] = acc[ii][jj][r] + bv;
            }
        }
    }
}

extern "C" void kernel_launch(void* const* d_in, const int* in_sizes, int n_in,
                              void* d_out, int out_size, void* d_ws, size_t ws_size,
                              hipStream_t stream) {
    const float* slots  = (const float*)d_in[0];   // 16*8*768
    const float* pos    = (const float*)d_in[1];   // 196*768
    // d_in[2] = map_alpha: unused (softmax over K of identical values = 1/K)
    const float* W1     = (const float*)d_in[3];   // 768*3072
    const float* b1     = (const float*)d_in[4];   // 3072
    const float* W2     = (const float*)d_in[5];   // 3072*768
    const float* b2     = (const float*)d_in[6];   // 768
    float* out = (float*)d_out;                    // 3136*768 f32

    size_t off = 0;
    auto alloc = [&](size_t bytes) {
        void* p = (char*)d_ws + off;
        off += (bytes + 255) & ~(size_t)255;
        return p;
    };
    unsigned short* W1t = (unsigned short*)alloc((size_t)3072 * 768 * 2);     // [48][12] atoms
    unsigned short* W2t = (unsigned short*)alloc((size_t)768 * 3072 * 2);     // [12][48] atoms
    unsigned short* A1  = (unsigned short*)alloc((size_t)384 * 768 * 2);      // [6][12] atoms
    float*          C1  = (float*)alloc((size_t)384 * 3072 * 4);              // row-major
    unsigned short* Hb  = (unsigned short*)alloc((size_t)50 * 48 * 4096 * 2); // [50][48] atoms

    // 1) prep: W1t + A1 (331776 tasks, 1296 blocks)
    k_prep<<<1296, 256, 0, stream>>>(W1, W1t, slots, pos, A1);
    // 2) GEMM1 (288 swizzled tiles) + W2t conversion (1152 blocks)
    k_gemm1_w2t<<<1440, 256, 0, stream>>>(A1, W1t, C1, W2, W2t);
    // 3) hbar -> Hb atoms (4800 blocks)
    k_hbar<<<4800, 256, 0, stream>>>(C1, b1, Hb);
    // 4) out = Hb @ W2t^T + b2 (300 blocks x 512 thr, rt-XCD swizzle)
    k_gemm2<<<300, 512, 0, stream>>>(Hb, W2t, b2, out);
}